// Round 7
// baseline (102.110 us; speedup 1.0000x reference)
//
#include <hip/hip_runtime.h>
#include <hip/hip_fp16.h>

// Bicubic (Catmull-Rom) warped interpolation.
// LDS-tiled (dual-phase f16) + register-prefetched deltas + packed-f16 math.
// img/delta_x/delta_y: [B,C,H,W] fp32; out: fp32 clipped to [0,1]. H=W=1024.
// 64x64 output tile / 256-thread block; 80x80 patch staged in LDS as f16 in
// TWO phase-shifted copies: copy0 dword j = elements (2j,2j+1); copy1 dword
// j = (2j+1,2j+2). Any 4-tap window lx..lx+3 = 2 adjacent dwords of copy
// (lx&1) -> one ds_read2_b32 per tap row (4 LDS instrs/pixel vs 16 b32).
// Vertical (wy) reduction in packed v_pk_fma_f16; horizontal (wx) in fp32.
// All 16 iterations' dx/dy loads hoisted into registers (HBM latency hidden).
// Out-of-patch taps (|delta| > ~6) take a rare fp32 global fallback.

#define HD 1024
#define WD 1024
#define TILE 64
#define HALO 8
#define SROWS 80          // staged rows
#define NPAIR 40          // valid f16-pairs (dwords) per row
#define PSTR 41           // dword stride per row (odd)
#define COFF 3296         // copy1 offset in dwords (80*41=3280, padded)

__device__ __forceinline__ float cubic_gather_global(
    const float* __restrict__ p, int x0, int y0,
    float wxm1, float wx0, float wx1, float wx2,
    float wym1, float wy0, float wy1, float wy2)
{
    int cx0 = min(max(x0 - 1, 0), WD - 1);
    int cx1 = min(max(x0,     0), WD - 1);
    int cx2 = min(max(x0 + 1, 0), WD - 1);
    int cx3 = min(max(x0 + 2, 0), WD - 1);
    int cy0 = min(max(y0 - 1, 0), HD - 1);
    int cy1 = min(max(y0,     0), HD - 1);
    int cy2 = min(max(y0 + 1, 0), HD - 1);
    int cy3 = min(max(y0 + 2, 0), HD - 1);
    const float* r0 = p + (size_t)cy0 * WD;
    const float* r1 = p + (size_t)cy1 * WD;
    const float* r2 = p + (size_t)cy2 * WD;
    const float* r3 = p + (size_t)cy3 * WD;
    float s0 = wxm1 * r0[cx0] + wx0 * r0[cx1] + wx1 * r0[cx2] + wx2 * r0[cx3];
    float s1 = wxm1 * r1[cx0] + wx0 * r1[cx1] + wx1 * r1[cx2] + wx2 * r1[cx3];
    float s2 = wxm1 * r2[cx0] + wx0 * r2[cx1] + wx1 * r2[cx2] + wx2 * r2[cx3];
    float s3 = wxm1 * r3[cx0] + wx0 * r3[cx1] + wx1 * r3[cx2] + wx2 * r3[cx3];
    return wym1 * s0 + wy0 * s1 + wy1 * s2 + wy2 * s3;
}

__global__ __launch_bounds__(256) void bicubic_tile_kernel(
    const float* __restrict__ img,
    const float* __restrict__ dxp,
    const float* __restrict__ dyp,
    float* __restrict__ out)
{
    __shared__ __half2 smp[2 * COFF];

    const int bx = blockIdx.x * TILE;
    const int by = blockIdx.y * TILE;
    const int plane = blockIdx.z;
    const float* __restrict__ p = img + (size_t)plane * (size_t)(HD * WD);

    const int gx0 = bx - HALO;
    const int gy0 = by - HALO;
    const int tid = threadIdx.x;

    // ---- stage 80 rows x 40 f16-pairs (x2 phase copies), edge-clamped ----
    if (gx0 >= 0 && gx0 + SROWS < WD) {   // can read gx0 .. gx0+80
        for (int s = tid; s < SROWS * (NPAIR / 2); s += 256) {
            int r = s / (NPAIR / 2);
            int q = s - r * (NPAIR / 2);
            int gy = min(max(gy0 + r, 0), HD - 1);
            const float* rowp = p + (size_t)gy * WD + gx0;
            float4 v = *reinterpret_cast<const float4*>(rowp + 4 * q);
            float v4 = rowp[4 * q + 4];
            int b = r * PSTR + 2 * q;
            __half h0 = __float2half(v.x), h1 = __float2half(v.y);
            __half h2 = __float2half(v.z), h3 = __float2half(v.w);
            __half h4 = __float2half(v4);
            smp[b]            = __halves2half2(h0, h1);   // copy0: (4q,   4q+1)
            smp[b + 1]        = __halves2half2(h2, h3);   // copy0: (4q+2, 4q+3)
            smp[COFF + b]     = __halves2half2(h1, h2);   // copy1: (4q+1, 4q+2)
            smp[COFF + b + 1] = __halves2half2(h3, h4);   // copy1: (4q+3, 4q+4)
        }
    } else {
        for (int s = tid; s < SROWS * NPAIR; s += 256) {
            int r = s / NPAIR;
            int j = s - r * NPAIR;
            int gy = min(max(gy0 + r, 0), HD - 1);
            const float* rowp = p + (size_t)gy * WD;
            int e0 = min(max(gx0 + 2 * j,     0), WD - 1);
            int e1 = min(max(gx0 + 2 * j + 1, 0), WD - 1);
            int e2 = min(max(gx0 + 2 * j + 2, 0), WD - 1);
            __half h0 = __float2half(rowp[e0]);
            __half h1 = __float2half(rowp[e1]);
            __half h2 = __float2half(rowp[e2]);
            int b = r * PSTR + j;
            smp[b]        = __halves2half2(h0, h1);
            smp[COFF + b] = __halves2half2(h1, h2);
        }
    }
    __syncthreads();

    // ---- compute: lane = column (64 consecutive cols/wave), 16 rows/thread
    const int col = bx + (tid & 63);
    const int rbase = by + (tid >> 6);
    const int didx0 = (plane << 20) | (rbase << 10) | col;

    // hoist ALL delta loads: issued back-to-back, consumed progressively ->
    // vmcnt tracking pipelines them and HBM latency hides under compute
    float vdx[16], vdy[16];
    #pragma unroll
    for (int it = 0; it < 16; ++it) {
        vdx[it] = dxp[didx0 + it * 4096];
        vdy[it] = dyp[didx0 + it * 4096];
    }

    // x_map = ((x + dx - 512)/511 + 1)*511.5 == (x-512)*s + 511.5 + dx*s
    const float s = 511.5f / 511.0f;
    const float colA = ((float)col - 512.0f) * s + 511.5f;
    const float yA0 = ((float)rbase - 512.0f) * s + 511.5f;
    const float yStep = 4.0f * s;

    #pragma unroll
    for (int it = 0; it < 16; ++it) {
        const int didx = didx0 + it * 4096;
        const float ddx = vdx[it];
        const float ddy = vdy[it];

        float x_map = fmaf(ddx, s, colA);
        float y_map = fmaf(ddy, s, yA0 + (float)it * yStep);

        float x0f = floorf(x_map);
        float y0f = floorf(y_map);
        float tx = x_map - x0f;
        float ty = y_map - y0f;
        int x0 = (int)x0f;
        int y0 = (int)y0f;

        float tx2 = tx * tx, tx3 = tx2 * tx;
        float wxm1 = (-tx3 + 2.0f * tx2 - tx) * 0.5f;
        float wx0  = (3.0f * tx3 - 5.0f * tx2 + 2.0f) * 0.5f;
        float wx1  = (-3.0f * tx3 + 4.0f * tx2 + tx) * 0.5f;
        float wx2  = 1.0f - (wxm1 + wx0 + wx1);

        float ty2 = ty * ty, ty3 = ty2 * ty;
        float wym1 = (-ty3 + 2.0f * ty2 - ty) * 0.5f;
        float wy0  = (3.0f * ty3 - 5.0f * ty2 + 2.0f) * 0.5f;
        float wy1  = (-3.0f * ty3 + 4.0f * ty2 + ty) * 0.5f;
        float wy2  = 1.0f - (wym1 + wy0 + wy1);

        const int lx = x0 - 1 - gx0;
        const int ly = y0 - 1 - gy0;
        const bool inb = (lx >= 0) & (lx <= SROWS - 4) & (ly >= 0) & (ly <= SROWS - 4);

        float acc;
        if (inb) {
            const __half2* bp = smp + ((lx & 1) ? COFF : 0) + ly * PSTR + (lx >> 1);
            __half2 d00 = bp[0],        d01 = bp[1];            // row 0
            __half2 d10 = bp[PSTR],     d11 = bp[PSTR + 1];     // row 1
            __half2 d20 = bp[2 * PSTR], d21 = bp[2 * PSTR + 1]; // row 2
            __half2 d30 = bp[3 * PSTR], d31 = bp[3 * PSTR + 1]; // row 3
            __half2 w0 = __float2half2_rn(wym1);
            __half2 w1 = __float2half2_rn(wy0);
            __half2 w2 = __float2half2_rn(wy1);
            __half2 w3 = __float2half2_rn(wy2);
            // vertical (wy) reduction in packed f16
            __half2 accA = __hmul2(w0, d00);
            __half2 accB = __hmul2(w0, d01);
            accA = __hfma2(w1, d10, accA);
            accB = __hfma2(w1, d11, accB);
            accA = __hfma2(w2, d20, accA);
            accB = __hfma2(w2, d21, accB);
            accA = __hfma2(w3, d30, accA);
            accB = __hfma2(w3, d31, accB);
            // horizontal (wx) combine in fp32
            acc = wxm1 * __low2float(accA) + wx0 * __high2float(accA)
                + wx1 * __low2float(accB) + wx2 * __high2float(accB);
        } else {
            acc = cubic_gather_global(p, x0, y0, wxm1, wx0, wx1, wx2,
                                      wym1, wy0, wy1, wy2);
        }
        out[didx] = fminf(fmaxf(acc, 0.0f), 1.0f);
    }
}

extern "C" void kernel_launch(void* const* d_in, const int* in_sizes, int n_in,
                              void* d_out, int out_size, void* d_ws, size_t ws_size,
                              hipStream_t stream) {
    const float* img = (const float*)d_in[0];
    const float* dxp = (const float*)d_in[1];
    const float* dyp = (const float*)d_in[2];
    float* out = (float*)d_out;

    const int planes = in_sizes[0] / (HD * WD);  // B*C = 24
    dim3 grid(WD / TILE, HD / TILE, planes);
    bicubic_tile_kernel<<<grid, 256, 0, stream>>>(img, dxp, dyp, out);
}